// Round 10
// baseline (269.589 us; speedup 1.0000x reference)
//
#include <hip/hip_runtime.h>

typedef _Float16 f16;
typedef _Float16 f16x8 __attribute__((ext_vector_type(8)));
typedef __fp16 fp16x2 __attribute__((ext_vector_type(2)));
typedef float f32x4 __attribute__((ext_vector_type(4)));
typedef float f32x16 __attribute__((ext_vector_type(16)));

#define CDIM 256
#define NPIX 9216
#define NB 8

__device__ __forceinline__ f32x4 mfma16(f16x8 a, f16x8 b, f32x4 c) {
  return __builtin_amdgcn_mfma_f32_16x16x32_f16(a, b, c, 0, 0, 0);
}
__device__ __forceinline__ f32x16 mfma32(f16x8 a, f16x8 b, f32x16 c) {
  return __builtin_amdgcn_mfma_f32_32x32x16_f16(a, b, c, 0, 0, 0);
}
__device__ __forceinline__ f16x8 ld8(const f16* p) { return *(const f16x8*)p; }

__device__ __forceinline__ void stage16(const void* g, void* l) {
  __builtin_amdgcn_global_load_lds((const __attribute__((address_space(1))) unsigned int*)g,
                                   (__attribute__((address_space(3))) unsigned int*)l, 16, 0, 0);
}
#define S_BARRIER() do { asm volatile("" ::: "memory"); __builtin_amdgcn_s_barrier(); asm volatile("" ::: "memory"); } while (0)
#define WAIT_VM(N) do { asm volatile("s_waitcnt vmcnt(" #N ")" ::: "memory"); __builtin_amdgcn_sched_barrier(0); } while (0)

__device__ __forceinline__ unsigned pkrtz(float a, float b) {
  union { fp16x2 h; unsigned u; } cv;
  cv.h = __builtin_amdgcn_cvt_pkrtz(a, b);
  return cv.u;
}
union U8 { f16x8 v; unsigned u[4]; };

// Pack 8 f32 (reg-order of a 32x32 D half-group) into f16x8 B-frag word order,
// exchanging quads with the lane^32 partner via shfl (verified R9).
__device__ __forceinline__ f16x8 pack_swap(float v0, float v1, float v2, float v3,
                                           float v4, float v5, float v6, float v7,
                                           int hh) {
  unsigned a  = pkrtz(v0, v1);
  unsigned b2 = pkrtz(v2, v3);
  unsigned c2 = pkrtz(v4, v5);
  unsigned d2 = pkrtz(v6, v7);
  unsigned ex1 = __shfl_xor(hh ? a : c2, 32);
  unsigned ex2 = __shfl_xor(hh ? b2 : d2, 32);
  U8 r;
  r.u[0] = hh ? ex1 : a;
  r.u[1] = hh ? ex2 : b2;
  r.u[2] = hh ? c2 : ex1;
  r.u[3] = hh ? d2 : ex2;
  return r.v;
}

// Frag conventions (32x32x16): A: lane(l31,h) holds A[row=l31][k=8h+e].
// B: lane(l31,h) holds B[k=8h+e][col=l31]. 1KB lane-linear frags (lane*16).
// D: col=lane&31, row=(reg&3)+8*(reg>>2)+4*(lane>>5).

// ---------------- K1: fold weights; WqF as 32x32-A frags ----------------
__global__ void prep_weights(const float* __restrict__ Wq,
                             const float* __restrict__ Wk, const float* __restrict__ bk,
                             const float* __restrict__ Wv, const float* __restrict__ bv,
                             const float* __restrict__ Ws, const float* __restrict__ bs,
                             f16* __restrict__ WqF, f16* __restrict__ Wk2H, f16* __restrict__ Wv2H,
                             float* __restrict__ bk2, float* __restrict__ bv2) {
  int o = blockIdx.x, c = threadIdx.x;
  float ak = 0.f, av = 0.f;
  for (int i = 0; i < CDIM; ++i) {
    float w = Ws[o*CDIM + i];
    ak += w * Wk[i*CDIM + c];
    av += w * Wv[i*CDIM + c];
  }
  Wk2H[o*CDIM + c] = (f16)ak;
  Wv2H[o*CDIM + c] = (f16)av;
  {
    size_t byte = (size_t)((o >> 5)*16 + (c >> 4))*1024
                + (size_t)(((c >> 3) & 1)*32 + (o & 31))*16 + (c & 7)*2;
    *(f16*)((char*)WqF + byte) = (f16)Wq[o*CDIM + c];
  }
  if (c == 0) {
    float sk = 0.f, sv = 0.f;
    for (int i = 0; i < CDIM; ++i) { float w = Ws[o*CDIM + i]; sk += w*bk[i]; sv += w*bv[i]; }
    bk2[o] = sk + bs[o];
    bv2[o] = sv + bs[o];
  }
}

// ---------------- K2: x[b][c][n] f32 -> xT swizzled [b][n][c] f16 ----------------
__global__ void transpose_x(const float* __restrict__ x, char* __restrict__ xT) {
  __shared__ f16 tile[32][34];   // [c][n]
  int c0 = blockIdx.x * 32, n0 = blockIdx.y * 32, b = blockIdx.z;
  int tx = threadIdx.x, ty = threadIdx.y;
#pragma unroll
  for (int j = 0; j < 4; ++j) {
    int cl = ty + 8*j;
    tile[cl][tx] = (f16)x[(size_t)(b*CDIM + c0 + cl)*NPIX + n0 + tx];
  }
  __syncthreads();
  int tid = ty*32 + tx;
  if (tid < 128) {
    int nl = tid >> 2, u = tid & 3;
    int n = n0 + nl;
    int cu = (c0 >> 3) + u;
    f16x8 v;
#pragma unroll
    for (int e = 0; e < 8; ++e) v[e] = tile[8*u + e][nl];
    size_t byte = (size_t)(b*NPIX + n)*512 + (size_t)((cu ^ (n & 7)) << 4);
    *(f16x8*)(xT + byte) = v;
  }
}

// ---------------- K3: K/V at subsampled pixels -> 32x32-frag-linear chunks ----------------
__global__ __launch_bounds__(256) void compute_kv(
    const char* __restrict__ xT, const f16* __restrict__ Wk2H, const f16* __restrict__ Wv2H,
    const float* __restrict__ bk2, const float* __restrict__ bv2,
    char* __restrict__ kB, char* __restrict__ vB) {
  int ch = blockIdx.x;            // key tile (32 keys)
  int m0 = ch * 32;
  int b = blockIdx.y;
  int tid = threadIdx.x;
  int w = tid >> 6, lane = tid & 63, l15 = lane & 15, q = lane >> 4;
  size_t chbase = (size_t)(b*32 + ch)*16384;

  const char* xrow[2]; int xn7[2];
#pragma unroll
  for (int mt2 = 0; mt2 < 2; ++mt2) {
    int m = m0 + 16*mt2 + l15;
    int n = 288*(m >> 5) + 3*(m & 31);   // subsampled pixel index
    xrow[mt2] = xT + (size_t)(b*NPIX + n)*512;
    xn7[mt2] = n & 7;
  }
  const f16 *kwb[4], *vwb[4];
#pragma unroll
  for (int t = 0; t < 4; ++t) {
    kwb[t] = Wk2H + (size_t)(64*w + 16*t + l15)*CDIM + 8*q;
    vwb[t] = Wv2H + (size_t)(64*w + 16*t + l15)*CDIM + 8*q;
  }
  f32x4 accK[2][4] = {};
  f32x4 accV[4][2] = {};
  for (int ks = 0; ks < 8; ++ks) {
    f16x8 am[2], wk[4], wv[4];
#pragma unroll
    for (int mt2 = 0; mt2 < 2; ++mt2)
      am[mt2] = *(const f16x8*)(xrow[mt2] + (((q + 4*ks) ^ xn7[mt2]) << 4));
#pragma unroll
    for (int t = 0; t < 4; ++t) { wk[t] = ld8(kwb[t] + 32*ks); wv[t] = ld8(vwb[t] + 32*ks); }
#pragma unroll
    for (int mt2 = 0; mt2 < 2; ++mt2)
#pragma unroll
      for (int ot = 0; ot < 4; ++ot) {
        accK[mt2][ot] = mfma16(am[mt2], wk[ot], accK[mt2][ot]);   // D[m][o]
        accV[ot][mt2] = mfma16(wv[ot], am[mt2], accV[ot][mt2]);   // D[c][m]
      }
  }
  // K writes: keyrel=16mt2+4q+r, cin=64w+16ot+l15
#pragma unroll
  for (int mt2 = 0; mt2 < 2; ++mt2)
#pragma unroll
    for (int ot = 0; ot < 4; ++ot) {
      int cin = 64*w + 16*ot + l15;
      float bo = bk2[cin];
      size_t fb = chbase + (size_t)(cin >> 4)*1024 + (size_t)(((cin >> 3) & 1)*32)*16 + (cin & 7)*2;
#pragma unroll
      for (int r = 0; r < 4; ++r) {
        int keyrel = 16*mt2 + 4*q + r;
        *(f16*)(kB + fb + (size_t)keyrel*16) = (f16)(accK[mt2][ot][r] + bo);
      }
    }
  // V writes: c=64w+16ct+4q+r, keyrel=16mt2+l15
#pragma unroll
  for (int ct = 0; ct < 4; ++ct) {
    f32x4 bv4 = *(const f32x4*)(bv2 + 64*w + 16*ct + 4*q);
#pragma unroll
    for (int mt2 = 0; mt2 < 2; ++mt2) {
#pragma unroll
      for (int r = 0; r < 4; ++r) {
        int c = 64*w + 16*ct + 4*q + r;
        size_t byte = chbase + (size_t)(2*(c >> 5) + mt2)*1024
                    + (size_t)((l15 >> 3)*32 + (c & 31))*16 + (l15 & 7)*2;
        *(f16*)(vB + byte) = (f16)(accV[ct][mt2][r] + bv4[r]);
      }
    }
  }
}

// ---------------- K4: attention, swapped-QK 32x32, c-split wave pairs ----------------
// 8 waves (512 thr): wave = (rt, cs); rt in 0..3 -> 32 q-rows, cs in 0..1 -> 128-ch half.
// Both cs-waves duplicate QK^T+softmax (bitwise identical); each does PV for its c-half.
// Cuts O to 64 regs/wave -> ~210 total -> 2 waves/SIMD.
__global__ __launch_bounds__(512, 2) void attention(
    const char* __restrict__ xT, const f16* __restrict__ WqF, const float* __restrict__ bq,
    const char* __restrict__ kB, const char* __restrict__ vB,
    const float* __restrict__ xg, const float* __restrict__ gamma_p,
    float* __restrict__ out) {
  __shared__ char lds[65536];    // [2][ K 16KB | V 16KB ]

  int bid = blockIdx.x;
  int b = bid & 7;               // XCD-bijective: 576 = 8*72
  int tile = bid >> 3;
  int tid = threadIdx.x;
  int w = tid >> 6, lane = tid & 63, l31 = lane & 31, hh = lane >> 5;
  int rt = w & 3, cs = w >> 2;
  int n0w = tile*128 + rt*32;    // this wave's q-row base
  int lane16 = lane * 16;

  const char* kBb = kB + (size_t)b*524288;
  const char* vBb = vB + (size_t)b*524288;

  // ---- stage K0/V0 early (hidden under phase A); 512 thr -> 2+2 ops ----
  {
    int so = tid * 16;
    stage16(kBb + so, lds + so);
    stage16(kBb + so + 8192, lds + so + 8192);
    stage16(vBb + so, lds + 16384 + so);
    stage16(vBb + so + 8192, lds + 16384 + so + 8192);
  }

  // ---- Phase A: per-wave Q build -> qf[16] B-frags (no LDS) ----
  f16x8 qf[16];
  {
    f16x8 xb[16];
    int n = n0w + l31;
    const char* xrow = xT + (size_t)(b*NPIX + n)*512;
    int n7 = n & 7;
#pragma unroll
    for (int s = 0; s < 16; ++s)
      xb[s] = *(const f16x8*)(xrow + (((2*s + hh) ^ n7) << 4));
#pragma unroll
    for (int ot = 0; ot < 8; ++ot) {
      f32x16 acc;
#pragma unroll
      for (int j = 0; j < 16; ++j) acc[j] = 0.f;
#pragma unroll
      for (int s = 0; s < 16; ++s) {
        f16x8 wa = *(const f16x8*)((const char*)WqF + (size_t)(ot*16 + s)*1024 + lane16);
        acc = mfma32(wa, xb[s], acc);    // D[o_rel][row=l31]
      }
#pragma unroll
      for (int i = 0; i < 4; ++i) {
        f32x4 bv4 = *(const f32x4*)(bq + 32*ot + 8*i + 4*hh);
#pragma unroll
        for (int j2 = 0; j2 < 4; ++j2) acc[4*i + j2] += bv4[j2];
      }
      qf[2*ot + 0] = pack_swap(acc[0], acc[1], acc[2], acc[3],
                               acc[4], acc[5], acc[6], acc[7], hh);
      qf[2*ot + 1] = pack_swap(acc[8], acc[9], acc[10], acc[11],
                               acc[12], acc[13], acc[14], acc[15], hh);
    }
  }

  // ---- main loop: 32 key-tiles, K/V double-buffer, counted vmcnt ----
  f32x16 O[4];
#pragma unroll
  for (int i = 0; i < 4; ++i)
#pragma unroll
    for (int j = 0; j < 16; ++j) O[i][j] = 0.f;
  float m_run = -3e38f, l_run = 0.f;

  for (int t = 0; t < 32; ++t) {
    char* curb = lds + ((t & 1) << 15);
    if (t < 31) {
      const char* ksrc = kBb + (size_t)(t + 1)*16384;
      const char* vsrc = vBb + (size_t)(t + 1)*16384;
      char* kd = lds + (((t + 1) & 1) << 15);
      int so = tid * 16;
      stage16(ksrc + so, kd + so);
      stage16(ksrc + so + 8192, kd + so + 8192);
      stage16(vsrc + so, kd + 16384 + so);
      stage16(vsrc + so + 8192, kd + 16384 + so + 8192);
      WAIT_VM(4);
    } else {
      WAIT_VM(0);
    }
    S_BARRIER();

    // QK^T: two 8-deep chains (Sa even s, Sb odd s) to halve dep latency
    f32x16 Sa, Sb;
#pragma unroll
    for (int j = 0; j < 16; ++j) { Sa[j] = 0.f; Sb[j] = 0.f; }
    __builtin_amdgcn_s_setprio(1);
#pragma unroll
    for (int s = 0; s < 8; ++s) {
      f16x8 kfa = *(const f16x8*)(curb + (2*s)*1024 + lane16);
      Sa = mfma32(kfa, qf[2*s], Sa);
      f16x8 kfb = *(const f16x8*)(curb + (2*s + 1)*1024 + lane16);
      Sb = mfma32(kfb, qf[2*s + 1], Sb);
    }
    __builtin_amdgcn_s_setprio(0);
    f32x16 S16;
#pragma unroll
    for (int j = 0; j < 16; ++j) S16[j] = Sa[j] + Sb[j];

    // lane-local softmax (identical in both cs-waves)
    float mx = S16[0];
#pragma unroll
    for (int j = 1; j < 16; ++j) mx = fmaxf(mx, S16[j]);
    mx = fmaxf(mx, __shfl_xor(mx, 32));
    if (!__all(mx <= m_run + 8.0f)) {    // T13 defer-max
      float mn = fmaxf(m_run, mx);
      float al = __expf(m_run - mn);
      m_run = mn;
      l_run *= al;
#pragma unroll
      for (int i = 0; i < 4; ++i)
#pragma unroll
        for (int j = 0; j < 16; ++j) O[i][j] *= al;
    }
    float p[16];
    float ls = 0.f;
#pragma unroll
    for (int j = 0; j < 16; ++j) { p[j] = __expf(S16[j] - m_run); ls += p[j]; }
    l_run += ls;

    // P -> f16 B-frags (shfl-based half exchange)
    f16x8 pf0 = pack_swap(p[0], p[1], p[2], p[3], p[4], p[5], p[6], p[7], hh);
    f16x8 pf1 = pack_swap(p[8], p[9], p[10], p[11], p[12], p[13], p[14], p[15], hh);

    // PV for this wave's c-half: O[c][row] += V[key][c] * P[row][key]
    __builtin_amdgcn_s_setprio(1);
#pragma unroll
    for (int ct = 0; ct < 4; ++ct) {
      int ctg = cs*4 + ct;
      f16x8 vf0 = *(const f16x8*)(curb + 16384 + (ctg*2 + 0)*1024 + lane16);
      O[ct] = mfma32(vf0, pf0, O[ct]);
      f16x8 vf1 = *(const f16x8*)(curb + 16384 + (ctg*2 + 1)*1024 + lane16);
      O[ct] = mfma32(vf1, pf1, O[ct]);
    }
    __builtin_amdgcn_s_setprio(0);
    S_BARRIER();
  }

  // ---- epilogue: out = gamma*O/l + x for this wave's c-half ----
  l_run += __shfl_xor(l_run, 32);
  float inv = 1.0f / l_run;
  float g = gamma_p[0];
  int n = n0w + l31;
#pragma unroll
  for (int ct = 0; ct < 4; ++ct)
#pragma unroll
    for (int j = 0; j < 16; ++j) {
      int c = 32*(cs*4 + ct) + (j & 3) + 8*(j >> 2) + 4*hh;
      size_t idx = (size_t)(b*CDIM + c)*NPIX + n;
      out[idx] = g * (O[ct][j] * inv) + xg[idx];
    }
}

extern "C" void kernel_launch(void* const* d_in, const int* in_sizes, int n_in,
                              void* d_out, int out_size, void* d_ws, size_t ws_size,
                              hipStream_t stream) {
  (void)in_sizes; (void)n_in; (void)out_size; (void)ws_size;
  const float* x     = (const float*)d_in[0];
  const float* Wq    = (const float*)d_in[1];
  const float* bq    = (const float*)d_in[2];
  const float* Wk    = (const float*)d_in[3];
  const float* bk    = (const float*)d_in[4];
  const float* Wv    = (const float*)d_in[5];
  const float* bv    = (const float*)d_in[6];
  const float* Ws    = (const float*)d_in[7];
  const float* bs    = (const float*)d_in[8];
  const float* gamma = (const float*)d_in[9];

  char* ws = (char*)d_ws;
  float* bk2 = (float*)(ws);
  float* bv2 = (float*)(ws + 1024);
  char* xT   = ws + 4096;
  char* kB   = ws + 4096 + 37748736;
  char* vB   = kB + 4194304;
  f16* WqF   = (f16*)(vB + 4194304);
  f16* Wk2H  = WqF + 65536;
  f16* Wv2H  = Wk2H + 65536;

  prep_weights<<<256, 256, 0, stream>>>(Wq, Wk, bk, Wv, bv, Ws, bs, WqF, Wk2H, Wv2H, bk2, bv2);
  transpose_x<<<dim3(8, 288, 8), dim3(32, 8), 0, stream>>>(x, xT);
  compute_kv<<<dim3(32, 8), 256, 0, stream>>>(xT, Wk2H, Wv2H, bk2, bv2, kB, vB);
  attention<<<576, 512, 0, stream>>>(xT, WqF, bq, kB, vB, x, gamma, (float*)d_out);
}

// Round 11
// 229.338 us; speedup vs baseline: 1.1755x; 1.1755x over previous
//
#include <hip/hip_runtime.h>

typedef _Float16 f16;
typedef _Float16 f16x8 __attribute__((ext_vector_type(8)));
typedef __fp16 fp16x2 __attribute__((ext_vector_type(2)));
typedef float f32x4 __attribute__((ext_vector_type(4)));
typedef float f32x16 __attribute__((ext_vector_type(16)));

#define CDIM 256
#define NPIX 9216
#define NB 8

__device__ __forceinline__ f32x4 mfma16(f16x8 a, f16x8 b, f32x4 c) {
  return __builtin_amdgcn_mfma_f32_16x16x32_f16(a, b, c, 0, 0, 0);
}
__device__ __forceinline__ f32x16 mfma32(f16x8 a, f16x8 b, f32x16 c) {
  return __builtin_amdgcn_mfma_f32_32x32x16_f16(a, b, c, 0, 0, 0);
}
__device__ __forceinline__ f16x8 ld8(const f16* p) { return *(const f16x8*)p; }

__device__ __forceinline__ void stage16(const void* g, void* l) {
  __builtin_amdgcn_global_load_lds((const __attribute__((address_space(1))) unsigned int*)g,
                                   (__attribute__((address_space(3))) unsigned int*)l, 16, 0, 0);
}
#define S_BARRIER() do { asm volatile("" ::: "memory"); __builtin_amdgcn_s_barrier(); asm volatile("" ::: "memory"); } while (0)
#define WAIT_VM(N) do { asm volatile("s_waitcnt vmcnt(" #N ")" ::: "memory"); __builtin_amdgcn_sched_barrier(0); } while (0)

__device__ __forceinline__ unsigned pkrtz(float a, float b) {
  union { fp16x2 h; unsigned u; } cv;
  cv.h = __builtin_amdgcn_cvt_pkrtz(a, b);
  return cv.u;
}
union U8 { f16x8 v; unsigned u[4]; };

// Pack 8 f32 (reg-order of a 32x32 D half-group) into f16x8 B-frag word order,
// exchanging quads with the lane^32 partner via shfl (verified R9).
__device__ __forceinline__ f16x8 pack_swap(float v0, float v1, float v2, float v3,
                                           float v4, float v5, float v6, float v7,
                                           int hh) {
  unsigned a  = pkrtz(v0, v1);
  unsigned b2 = pkrtz(v2, v3);
  unsigned c2 = pkrtz(v4, v5);
  unsigned d2 = pkrtz(v6, v7);
  unsigned ex1 = __shfl_xor(hh ? a : c2, 32);
  unsigned ex2 = __shfl_xor(hh ? b2 : d2, 32);
  U8 r;
  r.u[0] = hh ? ex1 : a;
  r.u[1] = hh ? ex2 : b2;
  r.u[2] = hh ? c2 : ex1;
  r.u[3] = hh ? d2 : ex2;
  return r.v;
}

// Frag conventions (32x32x16): A: lane(l31,h) holds A[row=l31][k=8h+e].
// B: lane(l31,h) holds B[k=8h+e][col=l31]. 1KB lane-linear frags (lane*16).
// D: col=lane&31, row=(reg&3)+8*(reg>>2)+4*(lane>>5).

// ---------------- K1: fold weights; WqF as 32x32-A frags ----------------
__global__ void prep_weights(const float* __restrict__ Wq,
                             const float* __restrict__ Wk, const float* __restrict__ bk,
                             const float* __restrict__ Wv, const float* __restrict__ bv,
                             const float* __restrict__ Ws, const float* __restrict__ bs,
                             f16* __restrict__ WqF, f16* __restrict__ Wk2H, f16* __restrict__ Wv2H,
                             float* __restrict__ bk2, float* __restrict__ bv2) {
  int o = blockIdx.x, c = threadIdx.x;
  float ak = 0.f, av = 0.f;
  for (int i = 0; i < CDIM; ++i) {
    float w = Ws[o*CDIM + i];
    ak += w * Wk[i*CDIM + c];
    av += w * Wv[i*CDIM + c];
  }
  Wk2H[o*CDIM + c] = (f16)ak;
  Wv2H[o*CDIM + c] = (f16)av;
  {
    size_t byte = (size_t)((o >> 5)*16 + (c >> 4))*1024
                + (size_t)(((c >> 3) & 1)*32 + (o & 31))*16 + (c & 7)*2;
    *(f16*)((char*)WqF + byte) = (f16)Wq[o*CDIM + c];
  }
  if (c == 0) {
    float sk = 0.f, sv = 0.f;
    for (int i = 0; i < CDIM; ++i) { float w = Ws[o*CDIM + i]; sk += w*bk[i]; sv += w*bv[i]; }
    bk2[o] = sk + bs[o];
    bv2[o] = sv + bs[o];
  }
}

// ---------------- K2: x[b][c][n] f32 -> xT swizzled [b][n][c] f16 ----------------
__global__ void transpose_x(const float* __restrict__ x, char* __restrict__ xT) {
  __shared__ f16 tile[32][34];   // [c][n]
  int c0 = blockIdx.x * 32, n0 = blockIdx.y * 32, b = blockIdx.z;
  int tx = threadIdx.x, ty = threadIdx.y;
#pragma unroll
  for (int j = 0; j < 4; ++j) {
    int cl = ty + 8*j;
    tile[cl][tx] = (f16)x[(size_t)(b*CDIM + c0 + cl)*NPIX + n0 + tx];
  }
  __syncthreads();
  int tid = ty*32 + tx;
  if (tid < 128) {
    int nl = tid >> 2, u = tid & 3;
    int n = n0 + nl;
    int cu = (c0 >> 3) + u;
    f16x8 v;
#pragma unroll
    for (int e = 0; e < 8; ++e) v[e] = tile[8*u + e][nl];
    size_t byte = (size_t)(b*NPIX + n)*512 + (size_t)((cu ^ (n & 7)) << 4);
    *(f16x8*)(xT + byte) = v;
  }
}

// ---------------- K3: K/V at subsampled pixels -> 32x32-frag-linear chunks ----------------
__global__ __launch_bounds__(256) void compute_kv(
    const char* __restrict__ xT, const f16* __restrict__ Wk2H, const f16* __restrict__ Wv2H,
    const float* __restrict__ bk2, const float* __restrict__ bv2,
    char* __restrict__ kB, char* __restrict__ vB) {
  int ch = blockIdx.x;            // key tile (32 keys)
  int m0 = ch * 32;
  int b = blockIdx.y;
  int tid = threadIdx.x;
  int w = tid >> 6, lane = tid & 63, l15 = lane & 15, q = lane >> 4;
  size_t chbase = (size_t)(b*32 + ch)*16384;

  const char* xrow[2]; int xn7[2];
#pragma unroll
  for (int mt2 = 0; mt2 < 2; ++mt2) {
    int m = m0 + 16*mt2 + l15;
    int n = 288*(m >> 5) + 3*(m & 31);   // subsampled pixel index
    xrow[mt2] = xT + (size_t)(b*NPIX + n)*512;
    xn7[mt2] = n & 7;
  }
  const f16 *kwb[4], *vwb[4];
#pragma unroll
  for (int t = 0; t < 4; ++t) {
    kwb[t] = Wk2H + (size_t)(64*w + 16*t + l15)*CDIM + 8*q;
    vwb[t] = Wv2H + (size_t)(64*w + 16*t + l15)*CDIM + 8*q;
  }
  f32x4 accK[2][4] = {};
  f32x4 accV[4][2] = {};
  for (int ks = 0; ks < 8; ++ks) {
    f16x8 am[2], wk[4], wv[4];
#pragma unroll
    for (int mt2 = 0; mt2 < 2; ++mt2)
      am[mt2] = *(const f16x8*)(xrow[mt2] + (((q + 4*ks) ^ xn7[mt2]) << 4));
#pragma unroll
    for (int t = 0; t < 4; ++t) { wk[t] = ld8(kwb[t] + 32*ks); wv[t] = ld8(vwb[t] + 32*ks); }
#pragma unroll
    for (int mt2 = 0; mt2 < 2; ++mt2)
#pragma unroll
      for (int ot = 0; ot < 4; ++ot) {
        accK[mt2][ot] = mfma16(am[mt2], wk[ot], accK[mt2][ot]);   // D[m][o]
        accV[ot][mt2] = mfma16(wv[ot], am[mt2], accV[ot][mt2]);   // D[c][m]
      }
  }
  // K writes: keyrel=16mt2+4q+r, cin=64w+16ot+l15
#pragma unroll
  for (int mt2 = 0; mt2 < 2; ++mt2)
#pragma unroll
    for (int ot = 0; ot < 4; ++ot) {
      int cin = 64*w + 16*ot + l15;
      float bo = bk2[cin];
      size_t fb = chbase + (size_t)(cin >> 4)*1024 + (size_t)(((cin >> 3) & 1)*32)*16 + (cin & 7)*2;
#pragma unroll
      for (int r = 0; r < 4; ++r) {
        int keyrel = 16*mt2 + 4*q + r;
        *(f16*)(kB + fb + (size_t)keyrel*16) = (f16)(accK[mt2][ot][r] + bo);
      }
    }
  // V writes: c=64w+16ct+4q+r, keyrel=16mt2+l15
#pragma unroll
  for (int ct = 0; ct < 4; ++ct) {
    f32x4 bv4 = *(const f32x4*)(bv2 + 64*w + 16*ct + 4*q);
#pragma unroll
    for (int mt2 = 0; mt2 < 2; ++mt2) {
#pragma unroll
      for (int r = 0; r < 4; ++r) {
        int c = 64*w + 16*ct + 4*q + r;
        size_t byte = chbase + (size_t)(2*(c >> 5) + mt2)*1024
                    + (size_t)((l15 >> 3)*32 + (c & 31))*16 + (l15 & 7)*2;
        *(f16*)(vB + byte) = (f16)(accV[ct][mt2][r] + bv4[r]);
      }
    }
  }
}

// ---------------- K4: attention, swapped-QK 32x32, 8 rt-waves (256 rows/block) ----------------
// 288 blocks (8b x 36 tiles) -> ~1.1 blocks/CU; 8 waves/block = 2 waves/SIMD
// co-resident by construction; launch_bounds(512,2) caps regs at 256/wave.
__global__ __launch_bounds__(512, 2) void attention(
    const char* __restrict__ xT, const f16* __restrict__ WqF, const float* __restrict__ bq,
    const char* __restrict__ kB, const char* __restrict__ vB,
    const float* __restrict__ xg, const float* __restrict__ gamma_p,
    float* __restrict__ out) {
  __shared__ char lds[65536];    // [2][ K 16KB | V 16KB ]

  int bid = blockIdx.x;
  int b = bid & 7;               // XCD-bijective: 288 = 8*36
  int tile = bid >> 3;
  int tid = threadIdx.x;
  int w = tid >> 6, lane = tid & 63, l31 = lane & 31, hh = lane >> 5;
  int n0w = tile*256 + w*32;     // this wave's q-row base
  int lane16 = lane * 16;

  const char* kBb = kB + (size_t)b*524288;
  const char* vBb = vB + (size_t)b*524288;

  // ---- stage K0/V0 early (hidden under phase A); 512 thr -> 2+2 ops ----
  {
    int so = tid * 16;
    stage16(kBb + so, lds + so);
    stage16(kBb + so + 8192, lds + so + 8192);
    stage16(vBb + so, lds + 16384 + so);
    stage16(vBb + so + 8192, lds + 16384 + so + 8192);
  }

  // ---- Phase A: per-wave Q build -> qf[16] B-frags (no LDS) ----
  f16x8 qf[16];
  {
    f16x8 xb[16];
    int n = n0w + l31;
    const char* xrow = xT + (size_t)(b*NPIX + n)*512;
    int n7 = n & 7;
#pragma unroll
    for (int s = 0; s < 16; ++s)
      xb[s] = *(const f16x8*)(xrow + (((2*s + hh) ^ n7) << 4));
#pragma unroll
    for (int ot = 0; ot < 8; ++ot) {
      f32x16 acc;
#pragma unroll
      for (int j = 0; j < 16; ++j) acc[j] = 0.f;
#pragma unroll
      for (int s = 0; s < 16; ++s) {
        f16x8 wa = *(const f16x8*)((const char*)WqF + (size_t)(ot*16 + s)*1024 + lane16);
        acc = mfma32(wa, xb[s], acc);    // D[o_rel][row=l31]
      }
#pragma unroll
      for (int i = 0; i < 4; ++i) {
        f32x4 bv4 = *(const f32x4*)(bq + 32*ot + 8*i + 4*hh);
#pragma unroll
        for (int j2 = 0; j2 < 4; ++j2) acc[4*i + j2] += bv4[j2];
      }
      qf[2*ot + 0] = pack_swap(acc[0], acc[1], acc[2], acc[3],
                               acc[4], acc[5], acc[6], acc[7], hh);
      qf[2*ot + 1] = pack_swap(acc[8], acc[9], acc[10], acc[11],
                               acc[12], acc[13], acc[14], acc[15], hh);
    }
  }

  // ---- main loop: 32 key-tiles, K/V double-buffer, counted vmcnt ----
  f32x16 O[8];
#pragma unroll
  for (int i = 0; i < 8; ++i)
#pragma unroll
    for (int j = 0; j < 16; ++j) O[i][j] = 0.f;
  float m_run = -3e38f, l_run = 0.f;

  for (int t = 0; t < 32; ++t) {
    char* curb = lds + ((t & 1) << 15);
    if (t < 31) {
      const char* ksrc = kBb + (size_t)(t + 1)*16384;
      const char* vsrc = vBb + (size_t)(t + 1)*16384;
      char* kd = lds + (((t + 1) & 1) << 15);
      int so = tid * 16;
      stage16(ksrc + so, kd + so);
      stage16(ksrc + so + 8192, kd + so + 8192);
      stage16(vsrc + so, kd + 16384 + so);
      stage16(vsrc + so + 8192, kd + 16384 + so + 8192);
      WAIT_VM(4);
    } else {
      WAIT_VM(0);
    }
    S_BARRIER();

    // QK^T: S[key][row], lane owns q-row l31; reg j -> key (j&3)+8*(j>>2)+4hh
    f32x16 S16;
#pragma unroll
    for (int j = 0; j < 16; ++j) S16[j] = 0.f;
    __builtin_amdgcn_s_setprio(1);
#pragma unroll
    for (int s = 0; s < 16; ++s) {
      f16x8 kf = *(const f16x8*)(curb + s*1024 + lane16);
      S16 = mfma32(kf, qf[s], S16);
    }
    __builtin_amdgcn_s_setprio(0);

    // lane-local softmax
    float mx = S16[0];
#pragma unroll
    for (int j = 1; j < 16; ++j) mx = fmaxf(mx, S16[j]);
    mx = fmaxf(mx, __shfl_xor(mx, 32));
    if (!__all(mx <= m_run + 8.0f)) {    // T13 defer-max
      float mn = fmaxf(m_run, mx);
      float al = __expf(m_run - mn);
      m_run = mn;
      l_run *= al;
#pragma unroll
      for (int i = 0; i < 8; ++i)
#pragma unroll
        for (int j = 0; j < 16; ++j) O[i][j] *= al;
    }
    float p[16];
    float ls = 0.f;
#pragma unroll
    for (int j = 0; j < 16; ++j) { p[j] = __expf(S16[j] - m_run); ls += p[j]; }
    l_run += ls;

    // P -> f16 B-frags (shfl-based half exchange)
    f16x8 pf0 = pack_swap(p[0], p[1], p[2], p[3], p[4], p[5], p[6], p[7], hh);
    f16x8 pf1 = pack_swap(p[8], p[9], p[10], p[11], p[12], p[13], p[14], p[15], hh);

    // PV: O[c][row] += V[key][c] * P[row][key]
    __builtin_amdgcn_s_setprio(1);
#pragma unroll
    for (int ct = 0; ct < 8; ++ct) {
      f16x8 vf0 = *(const f16x8*)(curb + 16384 + (ct*2 + 0)*1024 + lane16);
      O[ct] = mfma32(vf0, pf0, O[ct]);
      f16x8 vf1 = *(const f16x8*)(curb + 16384 + (ct*2 + 1)*1024 + lane16);
      O[ct] = mfma32(vf1, pf1, O[ct]);
    }
    __builtin_amdgcn_s_setprio(0);
    S_BARRIER();
  }

  // ---- epilogue: out = gamma*O/l + x ----
  l_run += __shfl_xor(l_run, 32);
  float inv = 1.0f / l_run;
  float g = gamma_p[0];
  int n = n0w + l31;
#pragma unroll
  for (int ct = 0; ct < 8; ++ct)
#pragma unroll
    for (int j = 0; j < 16; ++j) {
      int c = 32*ct + (j & 3) + 8*(j >> 2) + 4*hh;
      size_t idx = (size_t)(b*CDIM + c)*NPIX + n;
      out[idx] = g * (O[ct][j] * inv) + xg[idx];
    }
}

extern "C" void kernel_launch(void* const* d_in, const int* in_sizes, int n_in,
                              void* d_out, int out_size, void* d_ws, size_t ws_size,
                              hipStream_t stream) {
  (void)in_sizes; (void)n_in; (void)out_size; (void)ws_size;
  const float* x     = (const float*)d_in[0];
  const float* Wq    = (const float*)d_in[1];
  const float* bq    = (const float*)d_in[2];
  const float* Wk    = (const float*)d_in[3];
  const float* bk    = (const float*)d_in[4];
  const float* Wv    = (const float*)d_in[5];
  const float* bv    = (const float*)d_in[6];
  const float* Ws    = (const float*)d_in[7];
  const float* bs    = (const float*)d_in[8];
  const float* gamma = (const float*)d_in[9];

  char* ws = (char*)d_ws;
  float* bk2 = (float*)(ws);
  float* bv2 = (float*)(ws + 1024);
  char* xT   = ws + 4096;
  char* kB   = ws + 4096 + 37748736;
  char* vB   = kB + 4194304;
  f16* WqF   = (f16*)(vB + 4194304);
  f16* Wk2H  = WqF + 65536;
  f16* Wv2H  = Wk2H + 65536;

  prep_weights<<<256, 256, 0, stream>>>(Wq, Wk, bk, Wv, bv, Ws, bs, WqF, Wk2H, Wv2H, bk2, bv2);
  transpose_x<<<dim3(8, 288, 8), dim3(32, 8), 0, stream>>>(x, xT);
  compute_kv<<<dim3(32, 8), 256, 0, stream>>>(xT, Wk2H, Wv2H, bk2, bv2, kB, vB);
  attention<<<288, 512, 0, stream>>>(xT, WqF, bq, kB, vB, x, gamma, (float*)d_out);
}